// Round 15
// baseline (171.273 us; speedup 1.0000x reference)
//
#include <hip/hip_runtime.h>

#define NROWS  65536
#define CDIM   128
#define MKEYS  1024
#define BROWS  256    // rows per block (1 block/CU -- proven residency)
#define TROWS  16
#define NPAIRS 8      // 8 pairs x 32 rows
#define CANDCAP 8

typedef _Float16 half8 __attribute__((ext_vector_type(8)));
typedef _Float16 half4 __attribute__((ext_vector_type(4)));
typedef float    floatx4 __attribute__((ext_vector_type(4)));

union FU { float f; unsigned u; };

#define MFMA16 __builtin_amdgcn_mfma_f32_16x16x32_f16

// ---------------- Kernel A: convert keys fp32 -> fp16 in MFMA-fragment order --------
// Layout: for key k, dim d:  g=k>>4, n=k&15, f=d>>5, q8=(d&31)>>3, e=d&7
//   kh[ ((g*4+f)*64 + q8*16 + n)*8 + e ] = (fp16) keys[k][d]
__global__ __launch_bounds__(256) void cvt_keys_kernel(const float* __restrict__ keys,
                                                       _Float16* __restrict__ kh) {
    int i  = blockIdx.x * 256 + threadIdx.x;        // 32768 threads
    int k  = i >> 5;                                // key 0..1023
    int d0 = (i & 31) * 4;                          // dim 0,4,...,124
    float4 f4 = *(const float4*)(keys + (long)k * CDIM + d0);
    half4 hv;
    hv[0] = (_Float16)f4.x; hv[1] = (_Float16)f4.y;
    hv[2] = (_Float16)f4.z; hv[3] = (_Float16)f4.w;
    int g = k >> 4, n = k & 15;
    int f = d0 >> 5, q8 = (d0 & 31) >> 3, e = d0 & 7;
    long idx = ((long)((g * 4 + f) * 64 + q8 * 16 + n)) * 8 + e;
    *(half4*)(kh + idx) = hv;
}

// ---------------- Kernel B: keys-in-registers, held-scores single pass (R15) ---------
// = R12 (86us rocprof, proven) with pass2 DELETED: pass1 accumulates into 16 named
// persistent floatx4 accs (AGPR residents); after the threshold the candidate push
// is a register scan of the held scores. Candidate completeness is trivial (scanned
// values ARE pass1's values). cnt==1 -> exact argmax; cnt>1 -> exact fp32 rescore
// (lowest-key ties); cap overflow -> exact full rescan.
__global__ __launch_bounds__(512, 2) void gather_main(
    const float* __restrict__ q,      // trend_representation (65536x128)
    const float* __restrict__ rep,    // representation
    const float* __restrict__ keys,   // fp32 keys (1024x128)
    const float* __restrict__ vals,   // fp32 values
    const _Float16* __restrict__ kh,  // fp16 keys, fragment order (ws)
    float* __restrict__ out)          // [131072]: keys_g then values_g
{
    __shared__ _Float16 qh[2][TROWS][128];         // 8 KB: tile A / tile B
    __shared__ float qss[2][TROWS][17];
    __shared__ float wtv[8][2][TROWS];             // per-wave per-row max
    __shared__ int   candCnt[32];                  // r = tile*16 + row
    __shared__ int   candKey[32][CANDCAP];
    __shared__ int   rowOvf[32];
    __shared__ unsigned long long rowBest[32];
    __shared__ int   rowIdxAll[BROWS];

    const int t    = threadIdx.x;     // 0..511
    const int w    = t >> 6;          // wave 0..7 (owns keys w*128..w*128+127)
    const int lane = t & 63;
    const int n    = lane & 15;       // q-row (C col) in tile
    const int quad = lane >> 4;       // key sub-slice / C row group
    const long blk0 = (long)blockIdx.x * BROWS;

    // ---- preload this wave's 128 keys into 32 half8 registers (one burst) ----
    const _Float16* kb = kh + (long)w * 16384 + lane * 8;
#define KD(g) k##g##0, k##g##1, k##g##2, k##g##3
    half8 KD(0), KD(1), KD(2), KD(3), KD(4), KD(5), KD(6), KD(7);
#define KL(g) \
    k##g##0 = *(const half8*)(kb + ((g)*4 + 0) * 512); \
    k##g##1 = *(const half8*)(kb + ((g)*4 + 1) * 512); \
    k##g##2 = *(const half8*)(kb + ((g)*4 + 2) * 512); \
    k##g##3 = *(const half8*)(kb + ((g)*4 + 3) * 512);
    KL(0) KL(1) KL(2) KL(3) KL(4) KL(5) KL(6) KL(7)

#define ENCMAX(v_, key_, r_) {                                             \
        FU su; su.f = (v_);                                                \
        unsigned ord = (su.u & 0x80000000u) ? ~su.u : (su.u | 0x80000000u);\
        unsigned long long enc = ((unsigned long long)ord << 32)           \
                               | (unsigned)(1023 - (key_));                \
        atomicMax(&rowBest[r_], enc); }

    for (int pair = 0; pair < NPAIRS; ++pair) {
        const long g0 = blk0 + (long)pair * 32;    // rows g0..g0+31 (A:0-15, B:16-31)

        // ---- stage BOTH tiles (waves 0-3 -> A, 4-7 -> B) + reset pair state ----
        {
            int half = t >> 8, tt = t & 255;
            int row = tt >> 4, c8 = tt & 15;
            const float4* src =
                (const float4*)(q + (g0 + half * TROWS + row) * CDIM + c8 * 8);
            float4 a0 = src[0], a1 = src[1];
            qss[half][row][c8] = a0.x*a0.x + a0.y*a0.y + a0.z*a0.z + a0.w*a0.w
                               + a1.x*a1.x + a1.y*a1.y + a1.z*a1.z + a1.w*a1.w;
            half8 hv;
            hv[0] = (_Float16)a0.x; hv[1] = (_Float16)a0.y;
            hv[2] = (_Float16)a0.z; hv[3] = (_Float16)a0.w;
            hv[4] = (_Float16)a1.x; hv[5] = (_Float16)a1.y;
            hv[6] = (_Float16)a1.z; hv[7] = (_Float16)a1.w;
            int phys = c8 ^ (row & 7);
            *(half8*)&qh[half][row][phys * 8] = hv;
            if (t < 32) { candCnt[t] = 0; rowOvf[t] = 0; rowBest[t] = 0ull; }
        }
        __syncthreads();                                               // B1

        // ---- B-fragments for row n of both tiles (die after pass 1) ----
        int x = n & 7;
        int p0 = ((0 * 4 + quad) ^ x) * 8;
        int p1 = ((1 * 4 + quad) ^ x) * 8;
        int p2 = ((2 * 4 + quad) ^ x) * 8;
        int p3 = ((3 * 4 + quad) ^ x) * 8;
        half8 qfA0 = *(const half8*)&qh[0][n][p0];
        half8 qfA1 = *(const half8*)&qh[0][n][p1];
        half8 qfA2 = *(const half8*)&qh[0][n][p2];
        half8 qfA3 = *(const half8*)&qh[0][n][p3];
        half8 qfB0 = *(const half8*)&qh[1][n][p0];
        half8 qfB1 = *(const half8*)&qh[1][n][p1];
        half8 qfB2 = *(const half8*)&qh[1][n][p2];
        half8 qfB3 = *(const half8*)&qh[1][n][p3];

        // ---- pass 1 (single pass): 64-MFMA slab into HELD accumulators ----
#define DECLACC(g) floatx4 aA##g = {0.f,0.f,0.f,0.f}, aB##g = {0.f,0.f,0.f,0.f};
        DECLACC(0) DECLACC(1) DECLACC(2) DECLACC(3)
        DECLACC(4) DECLACC(5) DECLACC(6) DECLACC(7)
        float m1A = -3.4e38f, m1B = -3.4e38f;
#define P1AB(g) {                                                            \
        aA##g = MFMA16(k##g##0, qfA0, aA##g, 0, 0, 0);                       \
        aB##g = MFMA16(k##g##0, qfB0, aB##g, 0, 0, 0);                       \
        aA##g = MFMA16(k##g##1, qfA1, aA##g, 0, 0, 0);                       \
        aB##g = MFMA16(k##g##1, qfB1, aB##g, 0, 0, 0);                       \
        aA##g = MFMA16(k##g##2, qfA2, aA##g, 0, 0, 0);                       \
        aB##g = MFMA16(k##g##2, qfB2, aB##g, 0, 0, 0);                       \
        aA##g = MFMA16(k##g##3, qfA3, aA##g, 0, 0, 0);                       \
        aB##g = MFMA16(k##g##3, qfB3, aB##g, 0, 0, 0);                       \
        m1A = fmaxf(m1A,                                                     \
              fmaxf(fmaxf(aA##g[0], aA##g[1]), fmaxf(aA##g[2], aA##g[3])));  \
        m1B = fmaxf(m1B,                                                     \
              fmaxf(fmaxf(aB##g[0], aB##g[1]), fmaxf(aB##g[2], aB##g[3]))); }
        P1AB(0) P1AB(1) P1AB(2) P1AB(3) P1AB(4) P1AB(5) P1AB(6) P1AB(7)
        m1A = fmaxf(m1A, __shfl_xor(m1A, 16));
        m1A = fmaxf(m1A, __shfl_xor(m1A, 32));
        m1B = fmaxf(m1B, __shfl_xor(m1B, 16));
        m1B = fmaxf(m1B, __shfl_xor(m1B, 32));
        if (lane < TROWS) { wtv[w][0][n] = m1A; wtv[w][1][n] = m1B; }
        __syncthreads();                                               // B2

        // ---- thresholds, computed redundantly by every thread for its row n ----
        float M1A = wtv[0][0][n], M1B = wtv[0][1][n];
        #pragma unroll
        for (int ww = 1; ww < 8; ++ww) {
            M1A = fmaxf(M1A, wtv[ww][0][n]);
            M1B = fmaxf(M1B, wtv[ww][1][n]);
        }
        float qn2A = 0.f, qn2B = 0.f;
        #pragma unroll
        for (int j = 0; j < 16; ++j) { qn2A += qss[0][n][j]; qn2B += qss[1][n][j]; }
        // fp16 rounding: |s~ - s| <= 2^-10*1.01*||q||*||k||max(<=17) + slack
        float thrA = M1A - 2.f * (0.0168f * sqrtf(qn2A) + 0.002f) - 0.02f;
        float thrB = M1B - 2.f * (0.0168f * sqrtf(qn2B) + 0.002f) - 0.02f;

        // ---- candidate scan of HELD scores (replaces pass 2's 64 MFMA) ----
#define PUSHK(r_, K_) { int pp_ = atomicAdd(&candCnt[r_], 1);                \
        if (pp_ < CANDCAP) candKey[r_][pp_] = (K_); else rowOvf[r_] = 1; }
#define SCANG(g) {                                                           \
        int keyb = ((w * 8 + (g)) << 4) + (quad << 2);                       \
        if (aA##g[0] >= thrA) PUSHK(n, keyb);                                \
        if (aA##g[1] >= thrA) PUSHK(n, keyb + 1);                            \
        if (aA##g[2] >= thrA) PUSHK(n, keyb + 2);                            \
        if (aA##g[3] >= thrA) PUSHK(n, keyb + 3);                            \
        if (aB##g[0] >= thrB) PUSHK(16 + n, keyb);                           \
        if (aB##g[1] >= thrB) PUSHK(16 + n, keyb + 1);                       \
        if (aB##g[2] >= thrB) PUSHK(16 + n, keyb + 2);                       \
        if (aB##g[3] >= thrB) PUSHK(16 + n, keyb + 3); }
        SCANG(0) SCANG(1) SCANG(2) SCANG(3) SCANG(4) SCANG(5) SCANG(6) SCANG(7)
        __syncthreads();                                               // B3

        // ---- ballot-gated sparse exact resolve ----
        {
            int r32 = lane & 31;
            int cntL = candCnt[r32], ovL = rowOvf[r32];
            unsigned long long needMask = __ballot(!ovL && cntL > 1) & 0xffffffffull;
            unsigned long long ovfMask  = __ballot(ovL != 0) & 0xffffffffull;
            // multi-candidate rows: wave w rescores slot w (64-lane coalesced dot)
            while (needMask) {
                int rb = __builtin_ctzll(needMask); needMask &= needMask - 1;
                if (w < candCnt[rb]) {
                    int key = candKey[rb][w];
                    const float2 xq = *(const float2*)(q + (g0 + rb) * CDIM + lane * 2);
                    const float2 xk = *(const float2*)(keys + (long)key * CDIM + lane * 2);
                    float v = xq.x * xk.x + xq.y * xk.y;
                    v += __shfl_xor(v, 1);  v += __shfl_xor(v, 2);
                    v += __shfl_xor(v, 4);  v += __shfl_xor(v, 8);
                    v += __shfl_xor(v, 16); v += __shfl_xor(v, 32);
                    if (lane == 0) ENCMAX(v, key, rb);
                }
            }
            // overflow rows: exact full rescan (rigor path, ~never)
            while (ovfMask) {
                int rb = __builtin_ctzll(ovfMask); ovfMask &= ovfMask - 1;
                int grp = t >> 4, l16 = t & 15;
                const float* qp = q + (g0 + rb) * CDIM + l16 * 8;
                float4 xa = *(const float4*)(qp), xb = *(const float4*)(qp + 4);
                for (int it = 0; it < 32; ++it) {
                    int key = it * 32 + grp;
                    const float* kp2 = keys + (long)key * CDIM + l16 * 8;
                    float4 ya = *(const float4*)(kp2), yb = *(const float4*)(kp2 + 4);
                    float v = xa.x*ya.x + xa.y*ya.y + xa.z*ya.z + xa.w*ya.w
                            + xb.x*yb.x + xb.y*yb.y + xb.z*yb.z + xb.w*yb.w;
                    v += __shfl_xor(v, 1); v += __shfl_xor(v, 2);
                    v += __shfl_xor(v, 4); v += __shfl_xor(v, 8);
                    if (l16 == 0) ENCMAX(v, key, rb);
                }
            }
        }
        __syncthreads();                                               // B4

        // ---- decode 32 rows ----
        if (t < 32) {
            int cnt = candCnt[t];
            rowIdxAll[pair * 32 + t] =
                (!rowOvf[t] && cnt == 1)
                    ? candKey[t][0]
                    : (1023 - (int)(unsigned)(rowBest[t] & 0xffffffffull));
        }
    }
    __syncthreads();

    // ---- batched gather: 8 passes x 32 rows, 16 lanes per row ----
    {
        int l16 = t & 15;
        #pragma unroll 1
        for (int pass = 0; pass < BROWS / 32; ++pass) {
            int row = pass * 32 + (t >> 4);
            int idx = rowIdxAll[row];
            long g = blk0 + row;
            const float* qp  = q    + g * CDIM + l16 * 8;
            const float* kp2 = keys + (long)idx * CDIM + l16 * 8;
            const float* rp  = rep  + g * CDIM + l16 * 8;
            const float* vp  = vals + (long)idx * CDIM + l16 * 8;
            float4 qa = *(const float4*)(qp),  qb = *(const float4*)(qp + 4);
            float4 ka = *(const float4*)(kp2), kb4 = *(const float4*)(kp2 + 4);
            float4 ra = *(const float4*)(rp),  rb = *(const float4*)(rp + 4);
            float4 va = *(const float4*)(vp),  vb = *(const float4*)(vp + 4);
            float d0 = qa.x-ka.x, d1 = qa.y-ka.y, d2 = qa.z-ka.z, d3 = qa.w-ka.w;
            float d4 = qb.x-kb4.x, d5 = qb.y-kb4.y, d6 = qb.z-kb4.z, d7 = qb.w-kb4.w;
            float kg = d0*d0+d1*d1+d2*d2+d3*d3+d4*d4+d5*d5+d6*d6+d7*d7;
            float e0 = ra.x-va.x, e1 = ra.y-va.y, e2 = ra.z-va.z, e3 = ra.w-va.w;
            float e4 = rb.x-vb.x, e5 = rb.y-vb.y, e6 = rb.z-vb.z, e7 = rb.w-vb.w;
            float vg = e0*e0+e1*e1+e2*e2+e3*e3+e4*e4+e5*e5+e6*e6+e7*e7;
            kg += __shfl_xor(kg, 1); kg += __shfl_xor(kg, 2);
            kg += __shfl_xor(kg, 4); kg += __shfl_xor(kg, 8);
            vg += __shfl_xor(vg, 1); vg += __shfl_xor(vg, 2);
            vg += __shfl_xor(vg, 4); vg += __shfl_xor(vg, 8);
            if (l16 == 0) { out[g] = kg; out[NROWS + g] = vg; }
        }
    }
}

extern "C" void kernel_launch(void* const* d_in, const int* in_sizes, int n_in,
                              void* d_out, int out_size, void* d_ws, size_t ws_size,
                              hipStream_t stream) {
    const float* q    = (const float*)d_in[0];  // trend_representation
    const float* rep  = (const float*)d_in[1];  // representation
    const float* keys = (const float*)d_in[2];
    const float* vals = (const float*)d_in[3];
    _Float16* kh = (_Float16*)d_ws;             // 256 KB fp16 key cache (fragment order)

    cvt_keys_kernel<<<128, 256, 0, stream>>>(keys, kh);
    gather_main<<<NROWS / BROWS, 512, 0, stream>>>(q, rep, keys, vals, kh,
                                                   (float*)d_out);
}

// Round 16
// 148.087 us; speedup vs baseline: 1.1566x; 1.1566x over previous
//
#include <hip/hip_runtime.h>

#define NROWS  65536
#define CDIM   128
#define MKEYS  1024
#define BROWS  256    // rows per block (1 block/CU -- proven residency)
#define TROWS  16
#define NPAIRS 8
#define CANDCAP 8

typedef _Float16 half8 __attribute__((ext_vector_type(8)));
typedef _Float16 half4 __attribute__((ext_vector_type(4)));
typedef float    floatx4 __attribute__((ext_vector_type(4)));

union FU { float f; unsigned u; };

#define MFMA16 __builtin_amdgcn_mfma_f32_16x16x32_f16

// ---------------- Kernel A: convert keys fp32 -> fp16 in MFMA-fragment order --------
// Layout: for key k, dim d:  g=k>>4, n=k&15, f=d>>5, q8=(d&31)>>3, e=d&7
//   kh[ ((g*4+f)*64 + q8*16 + n)*8 + e ] = (fp16) keys[k][d]
__global__ __launch_bounds__(256) void cvt_keys_kernel(const float* __restrict__ keys,
                                                       _Float16* __restrict__ kh) {
    int i  = blockIdx.x * 256 + threadIdx.x;        // 32768 threads
    int k  = i >> 5;                                // key 0..1023
    int d0 = (i & 31) * 4;                          // dim 0,4,...,124
    float4 f4 = *(const float4*)(keys + (long)k * CDIM + d0);
    half4 hv;
    hv[0] = (_Float16)f4.x; hv[1] = (_Float16)f4.y;
    hv[2] = (_Float16)f4.z; hv[3] = (_Float16)f4.w;
    int g = k >> 4, n = k & 15;
    int f = d0 >> 5, q8 = (d0 & 31) >> 3, e = d0 & 7;
    long idx = ((long)((g * 4 + f) * 64 + q8 * 16 + n)) * 8 + e;
    *(half4*)(kh + idx) = hv;
}

// ---------------- Kernel B: keys-in-registers, TWO-STREAM pipeline (R16) -------------
// Per-stream dataflow == R12 (86us, proven): stage -> pass1(max) -> thr -> pass2
// (bit-identical recompute, push ALL keys >= thr) -> resolve -> decode. Streams A
// (even pairs) and B (odd pairs) run phase-shifted by 2 segments so every barrier
// segment pairs a latency phase (stage/resolve) with an MFMA slab. 19 barriers
// (R12: 32). No register state crosses barriers (fragments re-read from LDS).
// Resolve is wave-parallel (wave w takes needy rows w, w+8, ...).
__global__ __launch_bounds__(512, 2) void gather_main(
    const float* __restrict__ q,      // trend_representation (65536x128)
    const float* __restrict__ rep,    // representation
    const float* __restrict__ keys,   // fp32 keys (1024x128)
    const float* __restrict__ vals,   // fp32 values
    const _Float16* __restrict__ kh,  // fp16 keys, fragment order (ws)
    float* __restrict__ out)          // [131072]: keys_g then values_g
{
    __shared__ _Float16 qh[2][2][TROWS][128];      // 16 KB: [stream][tile][row][dim]
    __shared__ float qss[2][2][TROWS][17];
    __shared__ float wtv[2][8][2][TROWS];
    __shared__ int   candCnt[2][32];
    __shared__ int   candKey[2][32][CANDCAP];
    __shared__ int   rowOvf[2][32];
    __shared__ unsigned long long rowBest[2][32];
    __shared__ int   rowIdxAll[BROWS];

    const int t    = threadIdx.x;     // 0..511
    const int w    = t >> 6;          // wave 0..7 (owns keys w*128..w*128+127)
    const int lane = t & 63;
    const int n    = lane & 15;       // q-row (C col) in tile
    const int quad = lane >> 4;       // key sub-slice / C row group / 16-lane group
    const long blk0 = (long)blockIdx.x * BROWS;

    // ---- preload this wave's 128 keys into 32 half8 registers (one burst) ----
    const _Float16* kb = kh + (long)w * 16384 + lane * 8;
#define KD(g) k##g##0, k##g##1, k##g##2, k##g##3
    half8 KD(0), KD(1), KD(2), KD(3), KD(4), KD(5), KD(6), KD(7);
#define KL(g) \
    k##g##0 = *(const half8*)(kb + ((g)*4 + 0) * 512); \
    k##g##1 = *(const half8*)(kb + ((g)*4 + 1) * 512); \
    k##g##2 = *(const half8*)(kb + ((g)*4 + 2) * 512); \
    k##g##3 = *(const half8*)(kb + ((g)*4 + 3) * 512);
    KL(0) KL(1) KL(2) KL(3) KL(4) KL(5) KL(6) KL(7)

#define ENCMAX(S, v_, key_, r_) {                                          \
        FU su; su.f = (v_);                                                \
        unsigned ord = (su.u & 0x80000000u) ? ~su.u : (su.u | 0x80000000u);\
        unsigned long long enc = ((unsigned long long)ord << 32)           \
                               | (unsigned)(1023 - (key_));                \
        atomicMax(&rowBest[S][r_], enc); }

    // ---- phase macros (per-stream S, textual) ----
#define P1STAGE(S, g0_) {                                                    \
        int half_ = t >> 8, tt_ = t & 255;                                   \
        int row_ = tt_ >> 4, c8_ = tt_ & 15;                                 \
        const float4* src_ =                                                 \
            (const float4*)(q + ((g0_) + half_ * TROWS + row_) * CDIM + c8_ * 8); \
        float4 a0_ = src_[0], a1_ = src_[1];                                 \
        qss[S][half_][row_][c8_] =                                           \
              a0_.x*a0_.x + a0_.y*a0_.y + a0_.z*a0_.z + a0_.w*a0_.w          \
            + a1_.x*a1_.x + a1_.y*a1_.y + a1_.z*a1_.z + a1_.w*a1_.w;         \
        half8 hv_;                                                           \
        hv_[0] = (_Float16)a0_.x; hv_[1] = (_Float16)a0_.y;                  \
        hv_[2] = (_Float16)a0_.z; hv_[3] = (_Float16)a0_.w;                  \
        hv_[4] = (_Float16)a1_.x; hv_[5] = (_Float16)a1_.y;                  \
        hv_[6] = (_Float16)a1_.z; hv_[7] = (_Float16)a1_.w;                  \
        int phys_ = c8_ ^ (row_ & 7);                                        \
        *(half8*)&qh[S][half_][row_][phys_ * 8] = hv_;                       \
        if (t < 32) { candCnt[S][t] = 0; rowOvf[S][t] = 0;                   \
                      rowBest[S][t] = 0ull; }                                \
    }

#define FRAGS(S)                                                             \
        int x_ = n & 7;                                                      \
        int fp0_ = ((0 * 4 + quad) ^ x_) * 8;                                \
        int fp1_ = ((1 * 4 + quad) ^ x_) * 8;                                \
        int fp2_ = ((2 * 4 + quad) ^ x_) * 8;                                \
        int fp3_ = ((3 * 4 + quad) ^ x_) * 8;                                \
        half8 qfA0 = *(const half8*)&qh[S][0][n][fp0_];                      \
        half8 qfA1 = *(const half8*)&qh[S][0][n][fp1_];                      \
        half8 qfA2 = *(const half8*)&qh[S][0][n][fp2_];                      \
        half8 qfA3 = *(const half8*)&qh[S][0][n][fp3_];                      \
        half8 qfB0 = *(const half8*)&qh[S][1][n][fp0_];                      \
        half8 qfB1 = *(const half8*)&qh[S][1][n][fp1_];                      \
        half8 qfB2 = *(const half8*)&qh[S][1][n][fp2_];                      \
        half8 qfB3 = *(const half8*)&qh[S][1][n][fp3_];

#define P1AB(g) {                                                            \
        floatx4 aA = {0.f,0.f,0.f,0.f}, aB = {0.f,0.f,0.f,0.f};              \
        aA = MFMA16(k##g##0, qfA0, aA, 0, 0, 0);                             \
        aB = MFMA16(k##g##0, qfB0, aB, 0, 0, 0);                             \
        aA = MFMA16(k##g##1, qfA1, aA, 0, 0, 0);                             \
        aB = MFMA16(k##g##1, qfB1, aB, 0, 0, 0);                             \
        aA = MFMA16(k##g##2, qfA2, aA, 0, 0, 0);                             \
        aB = MFMA16(k##g##2, qfB2, aB, 0, 0, 0);                             \
        aA = MFMA16(k##g##3, qfA3, aA, 0, 0, 0);                             \
        aB = MFMA16(k##g##3, qfB3, aB, 0, 0, 0);                             \
        m1A = fmaxf(m1A, fmaxf(fmaxf(aA[0], aA[1]), fmaxf(aA[2], aA[3])));   \
        m1B = fmaxf(m1B, fmaxf(fmaxf(aB[0], aB[1]), fmaxf(aB[2], aB[3]))); }

#define P2PASS(S) {                                                          \
        FRAGS(S)                                                             \
        float m1A = -3.4e38f, m1B = -3.4e38f;                                \
        P1AB(0) P1AB(1) P1AB(2) P1AB(3) P1AB(4) P1AB(5) P1AB(6) P1AB(7)      \
        m1A = fmaxf(m1A, __shfl_xor(m1A, 16));                               \
        m1A = fmaxf(m1A, __shfl_xor(m1A, 32));                               \
        m1B = fmaxf(m1B, __shfl_xor(m1B, 16));                               \
        m1B = fmaxf(m1B, __shfl_xor(m1B, 32));                               \
        if (lane < TROWS) { wtv[S][w][0][n] = m1A; wtv[S][w][1][n] = m1B; }  \
    }

#define PUSHK(S, r_, K_) { int pp_ = atomicAdd(&candCnt[S][r_], 1);          \
        if (pp_ < CANDCAP) candKey[S][r_][pp_] = (K_);                       \
        else rowOvf[S][r_] = 1; }

#define P2AB(S, g) {                                                         \
        floatx4 aA = {0.f,0.f,0.f,0.f}, aB = {0.f,0.f,0.f,0.f};              \
        aA = MFMA16(k##g##0, qfA0, aA, 0, 0, 0);                             \
        aB = MFMA16(k##g##0, qfB0, aB, 0, 0, 0);                             \
        aA = MFMA16(k##g##1, qfA1, aA, 0, 0, 0);                             \
        aB = MFMA16(k##g##1, qfB1, aB, 0, 0, 0);                             \
        aA = MFMA16(k##g##2, qfA2, aA, 0, 0, 0);                             \
        aB = MFMA16(k##g##2, qfB2, aB, 0, 0, 0);                             \
        aA = MFMA16(k##g##3, qfA3, aA, 0, 0, 0);                             \
        aB = MFMA16(k##g##3, qfB3, aB, 0, 0, 0);                             \
        int keyb = ((w * 8 + (g)) << 4) + (quad << 2);                       \
        if (aA[0] >= thrA) PUSHK(S, n, keyb);                                \
        if (aA[1] >= thrA) PUSHK(S, n, keyb + 1);                            \
        if (aA[2] >= thrA) PUSHK(S, n, keyb + 2);                            \
        if (aA[3] >= thrA) PUSHK(S, n, keyb + 3);                            \
        if (aB[0] >= thrB) PUSHK(S, 16 + n, keyb);                           \
        if (aB[1] >= thrB) PUSHK(S, 16 + n, keyb + 1);                       \
        if (aB[2] >= thrB) PUSHK(S, 16 + n, keyb + 2);                       \
        if (aB[3] >= thrB) PUSHK(S, 16 + n, keyb + 3); }

#define P3PUSH(S) {                                                          \
        float M1A = wtv[S][0][0][n], M1B = wtv[S][0][1][n];                  \
        _Pragma("unroll")                                                    \
        for (int ww = 1; ww < 8; ++ww) {                                     \
            M1A = fmaxf(M1A, wtv[S][ww][0][n]);                              \
            M1B = fmaxf(M1B, wtv[S][ww][1][n]);                              \
        }                                                                    \
        float qn2A = 0.f, qn2B = 0.f;                                        \
        _Pragma("unroll")                                                    \
        for (int j = 0; j < 16; ++j) {                                       \
            qn2A += qss[S][0][n][j]; qn2B += qss[S][1][n][j];                \
        }                                                                    \
        float thrA = M1A - 2.f * (0.0168f * sqrtf(qn2A) + 0.002f) - 0.02f;   \
        float thrB = M1B - 2.f * (0.0168f * sqrtf(qn2B) + 0.002f) - 0.02f;   \
        FRAGS(S)                                                             \
        P2AB(S,0) P2AB(S,1) P2AB(S,2) P2AB(S,3)                              \
        P2AB(S,4) P2AB(S,5) P2AB(S,6) P2AB(S,7)                              \
    }

    // wave-parallel resolve: wave w handles needy-row bits w, w+8, ...
#define P4RESOLVE(S, g0_) {                                                  \
        int r32_ = lane & 31;                                                \
        int cntL_ = candCnt[S][r32_], ovL_ = rowOvf[S][r32_];                \
        unsigned long long needM_ = __ballot(!ovL_ && cntL_ > 1) & 0xffffffffull; \
        unsigned long long ovfM_  = __ballot(ovL_ != 0) & 0xffffffffull;     \
        unsigned long long m_ = needM_;                                      \
        int skip_ = w;                                                       \
        while (true) {                                                       \
            for (int s2_ = 0; s2_ < skip_ && m_; ++s2_) m_ &= m_ - 1;        \
            if (!m_) break;                                                  \
            int rb_ = __builtin_ctzll(m_); m_ &= m_ - 1; skip_ = 7;          \
            int cnt2_ = candCnt[S][rb_];                                     \
            const float* qp_ = q + ((g0_) + rb_) * CDIM + n * 8;             \
            float4 xa_ = *(const float4*)(qp_);                              \
            float4 xb_ = *(const float4*)(qp_ + 4);                          \
            for (int slot_ = quad; slot_ < cnt2_; slot_ += 4) {              \
                int key_ = candKey[S][rb_][slot_];                           \
                const float* kp_ = keys + (long)key_ * CDIM + n * 8;         \
                float4 ya_ = *(const float4*)(kp_);                          \
                float4 yb_ = *(const float4*)(kp_ + 4);                      \
                float v_ = xa_.x*ya_.x + xa_.y*ya_.y + xa_.z*ya_.z + xa_.w*ya_.w \
                         + xb_.x*yb_.x + xb_.y*yb_.y + xb_.z*yb_.z + xb_.w*yb_.w;\
                v_ += __shfl_xor(v_, 1); v_ += __shfl_xor(v_, 2);            \
                v_ += __shfl_xor(v_, 4); v_ += __shfl_xor(v_, 8);            \
                if (n == 0) ENCMAX(S, v_, key_, rb_);                        \
            }                                                                \
        }                                                                    \
        m_ = ovfM_; skip_ = w;                                               \
        while (true) {                                                       \
            for (int s2_ = 0; s2_ < skip_ && m_; ++s2_) m_ &= m_ - 1;        \
            if (!m_) break;                                                  \
            int rb_ = __builtin_ctzll(m_); m_ &= m_ - 1; skip_ = 7;          \
            const float* qp_ = q + ((g0_) + rb_) * CDIM + n * 8;             \
            float4 xa_ = *(const float4*)(qp_);                              \
            float4 xb_ = *(const float4*)(qp_ + 4);                          \
            for (int j_ = 0; j_ < 256; ++j_) {                               \
                int key_ = j_ * 4 + quad;                                    \
                const float* kp_ = keys + (long)key_ * CDIM + n * 8;         \
                float4 ya_ = *(const float4*)(kp_);                          \
                float4 yb_ = *(const float4*)(kp_ + 4);                      \
                float v_ = xa_.x*ya_.x + xa_.y*ya_.y + xa_.z*ya_.z + xa_.w*ya_.w \
                         + xb_.x*yb_.x + xb_.y*yb_.y + xb_.z*yb_.z + xb_.w*yb_.w;\
                v_ += __shfl_xor(v_, 1); v_ += __shfl_xor(v_, 2);            \
                v_ += __shfl_xor(v_, 4); v_ += __shfl_xor(v_, 8);            \
                if (n == 0) ENCMAX(S, v_, key_, rb_);                        \
            }                                                                \
        }                                                                    \
    }

#define DODECODE(S, p_) if (t < 32) {                                        \
        int cnt_ = candCnt[S][t];                                            \
        rowIdxAll[(p_) * 32 + t] =                                           \
            (!rowOvf[S][t] && cnt_ == 1)                                     \
                ? candKey[S][t][0]                                           \
                : (1023 - (int)(unsigned)(rowBest[S][t] & 0xffffffffull));   \
    }

    // ---- prologue ----
    P1STAGE(0, blk0);
    __syncthreads();
    P2PASS(0);
    __syncthreads();

    // ---- steady-state: 4 iterations, 2 pairs each, 4 barriers each ----
    for (int k = 0; k < 4; ++k) {
        const long gA = blk0 + (long)(2 * k) * 32;
        const long gB = blk0 + (long)(2 * k + 1) * 32;
        // seg a: decode B(prev) + stage B || pass2+push A
        if (k > 0) { DODECODE(1, 2 * k - 1); }
        P1STAGE(1, gB);
        P3PUSH(0);
        __syncthreads();
        // seg b: resolve A || pass1 B
        P4RESOLVE(0, gA);
        P2PASS(1);
        __syncthreads();
        // seg c: decode A + stage A(next) || pass2+push B
        DODECODE(0, 2 * k);
        if (k < 3) { P1STAGE(0, blk0 + (long)(2 * k + 2) * 32); }
        P3PUSH(1);
        __syncthreads();
        // seg d: resolve B || pass1 A(next)
        P4RESOLVE(1, gB);
        if (k < 3) { P2PASS(0); }
        __syncthreads();
    }
    DODECODE(1, 7);
    __syncthreads();

    // ---- batched gather: 8 passes x 32 rows, 16 lanes per row ----
    {
        int l16 = t & 15;
        #pragma unroll 1
        for (int pass = 0; pass < BROWS / 32; ++pass) {
            int row = pass * 32 + (t >> 4);
            int idx = rowIdxAll[row];
            long g = blk0 + row;
            const float* qp  = q    + g * CDIM + l16 * 8;
            const float* kp2 = keys + (long)idx * CDIM + l16 * 8;
            const float* rp  = rep  + g * CDIM + l16 * 8;
            const float* vp  = vals + (long)idx * CDIM + l16 * 8;
            float4 qa = *(const float4*)(qp),  qb = *(const float4*)(qp + 4);
            float4 ka = *(const float4*)(kp2), kb4 = *(const float4*)(kp2 + 4);
            float4 ra = *(const float4*)(rp),  rb = *(const float4*)(rp + 4);
            float4 va = *(const float4*)(vp),  vb = *(const float4*)(vp + 4);
            float d0 = qa.x-ka.x, d1 = qa.y-ka.y, d2 = qa.z-ka.z, d3 = qa.w-ka.w;
            float d4 = qb.x-kb4.x, d5 = qb.y-kb4.y, d6 = qb.z-kb4.z, d7 = qb.w-kb4.w;
            float kg = d0*d0+d1*d1+d2*d2+d3*d3+d4*d4+d5*d5+d6*d6+d7*d7;
            float e0 = ra.x-va.x, e1 = ra.y-va.y, e2 = ra.z-va.z, e3 = ra.w-va.w;
            float e4 = rb.x-vb.x, e5 = rb.y-vb.y, e6 = rb.z-vb.z, e7 = rb.w-vb.w;
            float vg = e0*e0+e1*e1+e2*e2+e3*e3+e4*e4+e5*e5+e6*e6+e7*e7;
            kg += __shfl_xor(kg, 1); kg += __shfl_xor(kg, 2);
            kg += __shfl_xor(kg, 4); kg += __shfl_xor(kg, 8);
            vg += __shfl_xor(vg, 1); vg += __shfl_xor(vg, 2);
            vg += __shfl_xor(vg, 4); vg += __shfl_xor(vg, 8);
            if (l16 == 0) { out[g] = kg; out[NROWS + g] = vg; }
        }
    }
}

extern "C" void kernel_launch(void* const* d_in, const int* in_sizes, int n_in,
                              void* d_out, int out_size, void* d_ws, size_t ws_size,
                              hipStream_t stream) {
    const float* q    = (const float*)d_in[0];  // trend_representation
    const float* rep  = (const float*)d_in[1];  // representation
    const float* keys = (const float*)d_in[2];
    const float* vals = (const float*)d_in[3];
    _Float16* kh = (_Float16*)d_ws;             // 256 KB fp16 key cache (fragment order)

    cvt_keys_kernel<<<128, 256, 0, stream>>>(keys, kh);
    gather_main<<<NROWS / BROWS, 512, 0, stream>>>(q, rep, keys, vals, kh,
                                                   (float*)d_out);
}

// Round 17
// 144.261 us; speedup vs baseline: 1.1872x; 1.0265x over previous
//
#include <hip/hip_runtime.h>

#define NROWS  65536
#define CDIM   128
#define MKEYS  1024
#define BROWS  256    // rows per block (1 block/CU -- proven residency)
#define TROWS  16
#define NPAIRS 8
#define CANDCAP 8

typedef _Float16 half8 __attribute__((ext_vector_type(8)));
typedef _Float16 half4 __attribute__((ext_vector_type(4)));
typedef float    floatx4 __attribute__((ext_vector_type(4)));

union FU { float f; unsigned u; };

#define MFMA16 __builtin_amdgcn_mfma_f32_16x16x32_f16

// ---------------- Kernel A: convert keys fp32 -> fp16 in MFMA-fragment order --------
// Layout: for key k, dim d:  g=k>>4, n=k&15, f=d>>5, q8=(d&31)>>3, e=d&7
//   kh[ ((g*4+f)*64 + q8*16 + n)*8 + e ] = (fp16) keys[k][d]
__global__ __launch_bounds__(256) void cvt_keys_kernel(const float* __restrict__ keys,
                                                       _Float16* __restrict__ kh) {
    int i  = blockIdx.x * 256 + threadIdx.x;        // 32768 threads
    int k  = i >> 5;                                // key 0..1023
    int d0 = (i & 31) * 4;                          // dim 0,4,...,124
    float4 f4 = *(const float4*)(keys + (long)k * CDIM + d0);
    half4 hv;
    hv[0] = (_Float16)f4.x; hv[1] = (_Float16)f4.y;
    hv[2] = (_Float16)f4.z; hv[3] = (_Float16)f4.w;
    int g = k >> 4, n = k & 15;
    int f = d0 >> 5, q8 = (d0 & 31) >> 3, e = d0 & 7;
    long idx = ((long)((g * 4 + f) * 64 + q8 * 16 + n)) * 8 + e;
    *(half4*)(kh + idx) = hv;
}

// ---------------- Kernel B: keys-in-registers, TWO-STREAM pipeline + fused gather ----
// = R16 (148us JSON, proven) with the end-of-block gather FOLDED into the pipeline:
// each pair's gather runs in the segment after its decode, overlapped with an MFMA
// slab + sparse resolve. Only pair 7's gather remains as tail. Everything else
// byte-identical to R16 (per-stream dataflow == R12's proven chain).
__global__ __launch_bounds__(512, 2) void gather_main(
    const float* __restrict__ q,      // trend_representation (65536x128)
    const float* __restrict__ rep,    // representation
    const float* __restrict__ keys,   // fp32 keys (1024x128)
    const float* __restrict__ vals,   // fp32 values
    const _Float16* __restrict__ kh,  // fp16 keys, fragment order (ws)
    float* __restrict__ out)          // [131072]: keys_g then values_g
{
    __shared__ _Float16 qh[2][2][TROWS][128];      // 16 KB: [stream][tile][row][dim]
    __shared__ float qss[2][2][TROWS][17];
    __shared__ float wtv[2][8][2][TROWS];
    __shared__ int   candCnt[2][32];
    __shared__ int   candKey[2][32][CANDCAP];
    __shared__ int   rowOvf[2][32];
    __shared__ unsigned long long rowBest[2][32];
    __shared__ int   rowIdxAll[BROWS];

    const int t    = threadIdx.x;     // 0..511
    const int w    = t >> 6;          // wave 0..7 (owns keys w*128..w*128+127)
    const int lane = t & 63;
    const int n    = lane & 15;       // q-row (C col) in tile
    const int quad = lane >> 4;       // key sub-slice / C row group / 16-lane group
    const long blk0 = (long)blockIdx.x * BROWS;

    // ---- preload this wave's 128 keys into 32 half8 registers (one burst) ----
    const _Float16* kb = kh + (long)w * 16384 + lane * 8;
#define KD(g) k##g##0, k##g##1, k##g##2, k##g##3
    half8 KD(0), KD(1), KD(2), KD(3), KD(4), KD(5), KD(6), KD(7);
#define KL(g) \
    k##g##0 = *(const half8*)(kb + ((g)*4 + 0) * 512); \
    k##g##1 = *(const half8*)(kb + ((g)*4 + 1) * 512); \
    k##g##2 = *(const half8*)(kb + ((g)*4 + 2) * 512); \
    k##g##3 = *(const half8*)(kb + ((g)*4 + 3) * 512);
    KL(0) KL(1) KL(2) KL(3) KL(4) KL(5) KL(6) KL(7)

#define ENCMAX(S, v_, key_, r_) {                                          \
        FU su; su.f = (v_);                                                \
        unsigned ord = (su.u & 0x80000000u) ? ~su.u : (su.u | 0x80000000u);\
        unsigned long long enc = ((unsigned long long)ord << 32)           \
                               | (unsigned)(1023 - (key_));                \
        atomicMax(&rowBest[S][r_], enc); }

    // ---- phase macros (per-stream S, textual) ----
#define P1STAGE(S, g0_) {                                                    \
        int half_ = t >> 8, tt_ = t & 255;                                   \
        int row_ = tt_ >> 4, c8_ = tt_ & 15;                                 \
        const float4* src_ =                                                 \
            (const float4*)(q + ((g0_) + half_ * TROWS + row_) * CDIM + c8_ * 8); \
        float4 a0_ = src_[0], a1_ = src_[1];                                 \
        qss[S][half_][row_][c8_] =                                           \
              a0_.x*a0_.x + a0_.y*a0_.y + a0_.z*a0_.z + a0_.w*a0_.w          \
            + a1_.x*a1_.x + a1_.y*a1_.y + a1_.z*a1_.z + a1_.w*a1_.w;         \
        half8 hv_;                                                           \
        hv_[0] = (_Float16)a0_.x; hv_[1] = (_Float16)a0_.y;                  \
        hv_[2] = (_Float16)a0_.z; hv_[3] = (_Float16)a0_.w;                  \
        hv_[4] = (_Float16)a1_.x; hv_[5] = (_Float16)a1_.y;                  \
        hv_[6] = (_Float16)a1_.z; hv_[7] = (_Float16)a1_.w;                  \
        int phys_ = c8_ ^ (row_ & 7);                                        \
        *(half8*)&qh[S][half_][row_][phys_ * 8] = hv_;                       \
        if (t < 32) { candCnt[S][t] = 0; rowOvf[S][t] = 0;                   \
                      rowBest[S][t] = 0ull; }                                \
    }

#define FRAGS(S)                                                             \
        int x_ = n & 7;                                                      \
        int fp0_ = ((0 * 4 + quad) ^ x_) * 8;                                \
        int fp1_ = ((1 * 4 + quad) ^ x_) * 8;                                \
        int fp2_ = ((2 * 4 + quad) ^ x_) * 8;                                \
        int fp3_ = ((3 * 4 + quad) ^ x_) * 8;                                \
        half8 qfA0 = *(const half8*)&qh[S][0][n][fp0_];                      \
        half8 qfA1 = *(const half8*)&qh[S][0][n][fp1_];                      \
        half8 qfA2 = *(const half8*)&qh[S][0][n][fp2_];                      \
        half8 qfA3 = *(const half8*)&qh[S][0][n][fp3_];                      \
        half8 qfB0 = *(const half8*)&qh[S][1][n][fp0_];                      \
        half8 qfB1 = *(const half8*)&qh[S][1][n][fp1_];                      \
        half8 qfB2 = *(const half8*)&qh[S][1][n][fp2_];                      \
        half8 qfB3 = *(const half8*)&qh[S][1][n][fp3_];

#define P1AB(g) {                                                            \
        floatx4 aA = {0.f,0.f,0.f,0.f}, aB = {0.f,0.f,0.f,0.f};              \
        aA = MFMA16(k##g##0, qfA0, aA, 0, 0, 0);                             \
        aB = MFMA16(k##g##0, qfB0, aB, 0, 0, 0);                             \
        aA = MFMA16(k##g##1, qfA1, aA, 0, 0, 0);                             \
        aB = MFMA16(k##g##1, qfB1, aB, 0, 0, 0);                             \
        aA = MFMA16(k##g##2, qfA2, aA, 0, 0, 0);                             \
        aB = MFMA16(k##g##2, qfB2, aB, 0, 0, 0);                             \
        aA = MFMA16(k##g##3, qfA3, aA, 0, 0, 0);                             \
        aB = MFMA16(k##g##3, qfB3, aB, 0, 0, 0);                             \
        m1A = fmaxf(m1A, fmaxf(fmaxf(aA[0], aA[1]), fmaxf(aA[2], aA[3])));   \
        m1B = fmaxf(m1B, fmaxf(fmaxf(aB[0], aB[1]), fmaxf(aB[2], aB[3]))); }

#define P2PASS(S) {                                                          \
        FRAGS(S)                                                             \
        float m1A = -3.4e38f, m1B = -3.4e38f;                                \
        P1AB(0) P1AB(1) P1AB(2) P1AB(3) P1AB(4) P1AB(5) P1AB(6) P1AB(7)      \
        m1A = fmaxf(m1A, __shfl_xor(m1A, 16));                               \
        m1A = fmaxf(m1A, __shfl_xor(m1A, 32));                               \
        m1B = fmaxf(m1B, __shfl_xor(m1B, 16));                               \
        m1B = fmaxf(m1B, __shfl_xor(m1B, 32));                               \
        if (lane < TROWS) { wtv[S][w][0][n] = m1A; wtv[S][w][1][n] = m1B; }  \
    }

#define PUSHK(S, r_, K_) { int pp_ = atomicAdd(&candCnt[S][r_], 1);          \
        if (pp_ < CANDCAP) candKey[S][r_][pp_] = (K_);                       \
        else rowOvf[S][r_] = 1; }

#define P2AB(S, g) {                                                         \
        floatx4 aA = {0.f,0.f,0.f,0.f}, aB = {0.f,0.f,0.f,0.f};              \
        aA = MFMA16(k##g##0, qfA0, aA, 0, 0, 0);                             \
        aB = MFMA16(k##g##0, qfB0, aB, 0, 0, 0);                             \
        aA = MFMA16(k##g##1, qfA1, aA, 0, 0, 0);                             \
        aB = MFMA16(k##g##1, qfB1, aB, 0, 0, 0);                             \
        aA = MFMA16(k##g##2, qfA2, aA, 0, 0, 0);                             \
        aB = MFMA16(k##g##2, qfB2, aB, 0, 0, 0);                             \
        aA = MFMA16(k##g##3, qfA3, aA, 0, 0, 0);                             \
        aB = MFMA16(k##g##3, qfB3, aB, 0, 0, 0);                             \
        int keyb = ((w * 8 + (g)) << 4) + (quad << 2);                       \
        if (aA[0] >= thrA) PUSHK(S, n, keyb);                                \
        if (aA[1] >= thrA) PUSHK(S, n, keyb + 1);                            \
        if (aA[2] >= thrA) PUSHK(S, n, keyb + 2);                            \
        if (aA[3] >= thrA) PUSHK(S, n, keyb + 3);                            \
        if (aB[0] >= thrB) PUSHK(S, 16 + n, keyb);                           \
        if (aB[1] >= thrB) PUSHK(S, 16 + n, keyb + 1);                       \
        if (aB[2] >= thrB) PUSHK(S, 16 + n, keyb + 2);                       \
        if (aB[3] >= thrB) PUSHK(S, 16 + n, keyb + 3); }

#define P3PUSH(S) {                                                          \
        float M1A = wtv[S][0][0][n], M1B = wtv[S][0][1][n];                  \
        _Pragma("unroll")                                                    \
        for (int ww = 1; ww < 8; ++ww) {                                     \
            M1A = fmaxf(M1A, wtv[S][ww][0][n]);                              \
            M1B = fmaxf(M1B, wtv[S][ww][1][n]);                              \
        }                                                                    \
        float qn2A = 0.f, qn2B = 0.f;                                        \
        _Pragma("unroll")                                                    \
        for (int j = 0; j < 16; ++j) {                                       \
            qn2A += qss[S][0][n][j]; qn2B += qss[S][1][n][j];                \
        }                                                                    \
        float thrA = M1A - 2.f * (0.0168f * sqrtf(qn2A) + 0.002f) - 0.02f;   \
        float thrB = M1B - 2.f * (0.0168f * sqrtf(qn2B) + 0.002f) - 0.02f;   \
        FRAGS(S)                                                             \
        P2AB(S,0) P2AB(S,1) P2AB(S,2) P2AB(S,3)                              \
        P2AB(S,4) P2AB(S,5) P2AB(S,6) P2AB(S,7)                              \
    }

    // wave-parallel resolve: wave w handles needy-row bits w, w+8, ...
#define P4RESOLVE(S, g0_) {                                                  \
        int r32_ = lane & 31;                                                \
        int cntL_ = candCnt[S][r32_], ovL_ = rowOvf[S][r32_];                \
        unsigned long long needM_ = __ballot(!ovL_ && cntL_ > 1) & 0xffffffffull; \
        unsigned long long ovfM_  = __ballot(ovL_ != 0) & 0xffffffffull;     \
        unsigned long long m_ = needM_;                                      \
        int skip_ = w;                                                       \
        while (true) {                                                       \
            for (int s2_ = 0; s2_ < skip_ && m_; ++s2_) m_ &= m_ - 1;        \
            if (!m_) break;                                                  \
            int rb_ = __builtin_ctzll(m_); m_ &= m_ - 1; skip_ = 7;          \
            int cnt2_ = candCnt[S][rb_];                                     \
            const float* qp_ = q + ((g0_) + rb_) * CDIM + n * 8;             \
            float4 xa_ = *(const float4*)(qp_);                              \
            float4 xb_ = *(const float4*)(qp_ + 4);                          \
            for (int slot_ = quad; slot_ < cnt2_; slot_ += 4) {              \
                int key_ = candKey[S][rb_][slot_];                           \
                const float* kp_ = keys + (long)key_ * CDIM + n * 8;         \
                float4 ya_ = *(const float4*)(kp_);                          \
                float4 yb_ = *(const float4*)(kp_ + 4);                      \
                float v_ = xa_.x*ya_.x + xa_.y*ya_.y + xa_.z*ya_.z + xa_.w*ya_.w \
                         + xb_.x*yb_.x + xb_.y*yb_.y + xb_.z*yb_.z + xb_.w*yb_.w;\
                v_ += __shfl_xor(v_, 1); v_ += __shfl_xor(v_, 2);            \
                v_ += __shfl_xor(v_, 4); v_ += __shfl_xor(v_, 8);            \
                if (n == 0) ENCMAX(S, v_, key_, rb_);                        \
            }                                                                \
        }                                                                    \
        m_ = ovfM_; skip_ = w;                                               \
        while (true) {                                                       \
            for (int s2_ = 0; s2_ < skip_ && m_; ++s2_) m_ &= m_ - 1;        \
            if (!m_) break;                                                  \
            int rb_ = __builtin_ctzll(m_); m_ &= m_ - 1; skip_ = 7;          \
            const float* qp_ = q + ((g0_) + rb_) * CDIM + n * 8;             \
            float4 xa_ = *(const float4*)(qp_);                              \
            float4 xb_ = *(const float4*)(qp_ + 4);                          \
            for (int j_ = 0; j_ < 256; ++j_) {                               \
                int key_ = j_ * 4 + quad;                                    \
                const float* kp_ = keys + (long)key_ * CDIM + n * 8;         \
                float4 ya_ = *(const float4*)(kp_);                          \
                float4 yb_ = *(const float4*)(kp_ + 4);                      \
                float v_ = xa_.x*ya_.x + xa_.y*ya_.y + xa_.z*ya_.z + xa_.w*ya_.w \
                         + xb_.x*yb_.x + xb_.y*yb_.y + xb_.z*yb_.z + xb_.w*yb_.w;\
                v_ += __shfl_xor(v_, 1); v_ += __shfl_xor(v_, 2);            \
                v_ += __shfl_xor(v_, 4); v_ += __shfl_xor(v_, 8);            \
                if (n == 0) ENCMAX(S, v_, key_, rb_);                        \
            }                                                                \
        }                                                                    \
    }

#define DODECODE(S, p_) if (t < 32) {                                        \
        int cnt_ = candCnt[S][t];                                            \
        rowIdxAll[(p_) * 32 + t] =                                           \
            (!rowOvf[S][t] && cnt_ == 1)                                     \
                ? candKey[S][t][0]                                           \
                : (1023 - (int)(unsigned)(rowBest[S][t] & 0xffffffffull));   \
    }

    // fused per-pair gather: 32 rows x 16 lanes (all 512 threads), one pass.
    // Reads rowIdxAll[p_*32..] (decoded before the preceding barrier).
#define GATHER32(p_) {                                                       \
        int l16_ = t & 15;                                                   \
        int row_ = (p_) * 32 + (t >> 4);                                     \
        int idx_ = rowIdxAll[row_];                                          \
        long g_ = blk0 + row_;                                               \
        const float* qp_  = q    + g_ * CDIM + l16_ * 8;                     \
        const float* kp_  = keys + (long)idx_ * CDIM + l16_ * 8;             \
        const float* rp_  = rep  + g_ * CDIM + l16_ * 8;                     \
        const float* vp_  = vals + (long)idx_ * CDIM + l16_ * 8;             \
        float4 qa_ = *(const float4*)(qp_),  qb_ = *(const float4*)(qp_ + 4);\
        float4 ka_ = *(const float4*)(kp_),  kb_ = *(const float4*)(kp_ + 4);\
        float4 ra_ = *(const float4*)(rp_),  rb_ = *(const float4*)(rp_ + 4);\
        float4 va_ = *(const float4*)(vp_),  vb_ = *(const float4*)(vp_ + 4);\
        float d0_ = qa_.x-ka_.x, d1_ = qa_.y-ka_.y;                          \
        float d2_ = qa_.z-ka_.z, d3_ = qa_.w-ka_.w;                          \
        float d4_ = qb_.x-kb_.x, d5_ = qb_.y-kb_.y;                          \
        float d6_ = qb_.z-kb_.z, d7_ = qb_.w-kb_.w;                          \
        float kg_ = d0_*d0_+d1_*d1_+d2_*d2_+d3_*d3_                          \
                  + d4_*d4_+d5_*d5_+d6_*d6_+d7_*d7_;                         \
        float e0_ = ra_.x-va_.x, e1_ = ra_.y-va_.y;                          \
        float e2_ = ra_.z-va_.z, e3_ = ra_.w-va_.w;                          \
        float e4_ = rb_.x-vb_.x, e5_ = rb_.y-vb_.y;                          \
        float e6_ = rb_.z-vb_.z, e7_ = rb_.w-vb_.w;                          \
        float vg_ = e0_*e0_+e1_*e1_+e2_*e2_+e3_*e3_                          \
                  + e4_*e4_+e5_*e5_+e6_*e6_+e7_*e7_;                         \
        kg_ += __shfl_xor(kg_, 1); kg_ += __shfl_xor(kg_, 2);                \
        kg_ += __shfl_xor(kg_, 4); kg_ += __shfl_xor(kg_, 8);                \
        vg_ += __shfl_xor(vg_, 1); vg_ += __shfl_xor(vg_, 2);                \
        vg_ += __shfl_xor(vg_, 4); vg_ += __shfl_xor(vg_, 8);                \
        if (l16_ == 0) { out[g_] = kg_; out[NROWS + g_] = vg_; }             \
    }

    // ---- prologue ----
    P1STAGE(0, blk0);
    __syncthreads();
    P2PASS(0);
    __syncthreads();

    // ---- steady-state: 4 iterations, 2 pairs each, 4 barriers each ----
    for (int k = 0; k < 4; ++k) {
        const long gA = blk0 + (long)(2 * k) * 32;
        const long gB = blk0 + (long)(2 * k + 1) * 32;
        // seg a: decode B(prev) + stage B || pass2+push A
        if (k > 0) { DODECODE(1, 2 * k - 1); }
        P1STAGE(1, gB);
        P3PUSH(0);
        __syncthreads();
        // seg b: resolve A || pass1 B || gather B(prev)
        P4RESOLVE(0, gA);
        P2PASS(1);
        if (k > 0) { GATHER32(2 * k - 1); }
        __syncthreads();
        // seg c: decode A + stage A(next) || pass2+push B
        DODECODE(0, 2 * k);
        if (k < 3) { P1STAGE(0, blk0 + (long)(2 * k + 2) * 32); }
        P3PUSH(1);
        __syncthreads();
        // seg d: resolve B || pass1 A(next) || gather A
        P4RESOLVE(1, gB);
        if (k < 3) { P2PASS(0); }
        GATHER32(2 * k);
        __syncthreads();
    }
    // ---- epilogue: decode + gather final pair (7) ----
    DODECODE(1, 7);
    __syncthreads();
    GATHER32(7);
}

extern "C" void kernel_launch(void* const* d_in, const int* in_sizes, int n_in,
                              void* d_out, int out_size, void* d_ws, size_t ws_size,
                              hipStream_t stream) {
    const float* q    = (const float*)d_in[0];  // trend_representation
    const float* rep  = (const float*)d_in[1];  // representation
    const float* keys = (const float*)d_in[2];
    const float* vals = (const float*)d_in[3];
    _Float16* kh = (_Float16*)d_ws;             // 256 KB fp16 key cache (fragment order)

    cvt_keys_kernel<<<128, 256, 0, stream>>>(keys, kh);
    gather_main<<<NROWS / BROWS, 512, 0, stream>>>(q, rep, keys, vals, kh,
                                                   (float*)d_out);
}